// Round 2
// baseline (203.946 us; speedup 1.0000x reference)
//
#include <hip/hip_runtime.h>
#include <hip/hip_bf16.h>
#include <stdint.h>

#define N_NODES 20000
#define N_EDGES 640000
#define FEAT 128
#define CAPD 128   // per-dst list cap; deg ~ Poisson(32), P(>128) ~ 1e-43
#define NPHASE 8   // o-feature slices of 16 (2.56 MB h-slice per phase, L2-resident)

typedef __attribute__((ext_vector_type(8))) short bf16x8;
typedef __attribute__((ext_vector_type(4))) float f32x4;

// ---------- helpers ----------
// packed f32x2 -> bf16x2 (v_cvt_pk_bf16_f32), lo in low half
__device__ __forceinline__ unsigned pkbf16(float lo, float hi) {
  __hip_bfloat162 p = __float22bfloat162_rn(make_float2(lo, hi));
  return *reinterpret_cast<unsigned*>(&p);
}

// order-preserving encode: f32 -> RNE-rounded bf16 -> monotone u16
// (e = b ^ (sign ? 0xFFFF : 0x8000); u16 compare == float compare)
__device__ __forceinline__ unsigned short enc16(float f) {
  unsigned a = __float_as_uint(f);
  unsigned b = (a + 0x7FFFu + ((a >> 16) & 1u)) >> 16;  // RNE to bf16
  unsigned s = (unsigned)((int)a >> 31);                // 0 or ~0
  return (unsigned short)((b ^ 0x8000u) ^ (s & 0x7FFFu));
}

// inverse of enc16 (result as f32)
__device__ __forceinline__ float dec16(unsigned e) {
  unsigned b = (e & 0x8000u) ? (e ^ 0x8000u) : (e ^ 0xFFFFu);
  return __uint_as_float(b << 16);
}

// packed 2x u16 max (the whole inner-loop reduce)
__device__ __forceinline__ void pmax(unsigned& a, unsigned v) {
  asm("v_pk_max_u16 %0, %0, %1" : "+v"(a) : "v"(v));
}

#define PMX4(v)                                              \
  do {                                                       \
    pmax(a0, (v).x); pmax(a1, (v).y);                        \
    pmax(a2, (v).z); pmax(a3, (v).w);                        \
  } while (0)

// ---------- kernel 1: zero cnt + convert W -> bf16 ([o][f] layout) ----------
__global__ void init_kernel(const float* __restrict__ W,
                            unsigned short* __restrict__ Wbf,
                            int* __restrict__ cnt) {
  int i = blockIdx.x * 256 + threadIdx.x;
  if (i < N_NODES) cnt[i] = 0;
  if (i < FEAT * FEAT / 2) {
    float2 w = ((const float2*)W)[i];
    ((unsigned*)Wbf)[i] = pkbf16(w.x, w.y);
  }
}

// ---------- kernel 2: edge scatter into per-dst lists (pure TLP, no barrier) ----------
__global__ __launch_bounds__(256) void scatter_kernel(const int* __restrict__ ei,
                                                      int* __restrict__ cnt,
                                                      unsigned short* __restrict__ csr) {
  int e = blockIdx.x * 256 + threadIdx.x;
  int src = ei[e];
  int dst = ei[N_EDGES + e];
  int pos = atomicAdd(&cnt[dst], 1);
  if (pos < CAPD) csr[(size_t)dst * CAPD + pos] = (unsigned short)src;
}

// ---------- kernel 3: MFMA GEMM + bias -> h (order-preserving u16-encoded) ----------
__global__ __launch_bounds__(256) void gemm_kernel(
    const float4* __restrict__ x, const unsigned short* __restrict__ Wbf,
    const float* __restrict__ b, uint4* __restrict__ h) {
  // x-stage: [t][16 n][136 f] bf16 = 17408 B.  h-stage (aliased): [16 n][520] u16.
  __shared__ __align__(16) unsigned short sm[17408 / 2];
  const int tid = threadIdx.x;
  const int n0 = blockIdx.x * 16;

  // ---- stage x -> LDS bf16 [t][n][f] via v_cvt_pk_bf16_f32 ----
#pragma unroll
  for (int it = 0; it < 4; ++it) {
    int e = tid + it * 256;       // 16 n x 64 f-pairs
    int n = e >> 6, fp = e & 63;  // f = 2*fp
    float4 a = x[(size_t)(n0 + n) * 128 + 2 * fp];
    float4 c = x[(size_t)(n0 + n) * 128 + 2 * fp + 1];
    ((unsigned*)sm)[(0 * 16 + n) * 68 + fp] = pkbf16(a.x, c.x);
    ((unsigned*)sm)[(1 * 16 + n) * 68 + fp] = pkbf16(a.y, c.y);
    ((unsigned*)sm)[(2 * 16 + n) * 68 + fp] = pkbf16(a.z, c.z);
    ((unsigned*)sm)[(3 * 16 + n) * 68 + fp] = pkbf16(a.w, c.w);
  }

  __syncthreads();

  const int wv = tid >> 6;  // t
  const int l = tid & 63;
  const int col = l & 15;
  const int quad = l >> 4;

  f32x4 acc[8];
#pragma unroll
  for (int os = 0; os < 8; ++os) {
    float bv = b[os * 16 + col];
    acc[os] = (f32x4){bv, bv, bv, bv};
  }

#pragma unroll
  for (int k = 0; k < 4; ++k) {
    bf16x8 af = *(const bf16x8*)&sm[(wv * 16 + col) * 136 + k * 32 + quad * 8];
#pragma unroll
    for (int os = 0; os < 8; ++os) {
      bf16x8 bfv = *(const bf16x8*)&Wbf[(os * 16 + col) * 128 + k * 32 + quad * 8];
      acc[os] = __builtin_amdgcn_mfma_f32_16x16x32_bf16(af, bfv, acc[os], 0, 0, 0);
    }
  }

  __syncthreads();

  // C layout: D[m = quad*4 + r][o = os*16 + col]; h-stage LDS [n][o][t], row 520 u16.
  // Values stored ENCODED (enc16) so agg can use packed u16 max.
#pragma unroll
  for (int os = 0; os < 8; ++os) {
#pragma unroll
    for (int r = 0; r < 4; ++r) {
      sm[(quad * 4 + r) * 520 + (os * 16 + col) * 4 + wv] = enc16(acc[os][r]);
    }
  }
  __syncthreads();

#pragma unroll
  for (int it = 0; it < 4; ++it) {
    int e = tid + it * 256;
    int n = e >> 6, q = e & 63;
    uint4 v = *(const uint4*)&sm[n * 520 + q * 8];
    h[(size_t)(n0 + n) * 64 + q] = v;
  }
}

// ---------- kernel 4: o-phased max aggregation, packed-u16 domain ----------
// phase = blockIdx.x & 7 == XCD (round-robin dispatch): each XCD keeps its
// 2.56 MB h-slice resident in its private L2 for the whole kernel.
// One wave per dst per phase; one wave-load covers 8 sources (8 lanes x 16 B);
// inner reduce is v_pk_max_u16 (no unpack); decode only at output.
__global__ __launch_bounds__(256) void agg_kernel(
    const uint4* __restrict__ h, const int* __restrict__ cnt,
    const unsigned short* __restrict__ csr, float4* __restrict__ out) {
  const int bid = blockIdx.x;
  const int p = bid & 7;
  const int grp = bid >> 3;
  const int w = threadIdx.x >> 6;
  const int lane = threadIdx.x & 63;
  const int n = grp * 4 + w;
  const int sub = lane >> 3;  // source slot within a group of 8
  const int oq = lane & 7;    // o-pair slot (2 o x 4 t = 16 B)

  // speculative index reads (csr region always allocated; entries >= deg unused)
  int e1 = (int)csr[(size_t)n * CAPD + lane];
  int e2 = (int)csr[(size_t)n * CAPD + 64 + lane];
  int deg = cnt[n];
  deg = deg > CAPD ? CAPD : deg;
  int idx0 = __shfl(e1, 0);  // valid whenever deg > 0; used to pad tail groups

  unsigned a0 = 0x007F007Fu, a1 = a0, a2 = a0, a3 = a0;  // enc(-inf) packed

  const size_t pbase = (size_t)p * 8 + oq;
  int ngrp = (deg + 7) >> 3;
  int g = 0;
  for (; g + 2 <= ngrp; g += 2) {
    int s0 = g * 8 + sub;
    int s1 = s0 + 8;
    int srcA = __shfl((g < 8) ? e1 : e2, s0 & 63);
    int srcB = __shfl((g + 1 < 8) ? e1 : e2, s1 & 63);
    srcA = (s0 < deg) ? srcA : idx0;  // dup of idx0: harmless for max
    srcB = (s1 < deg) ? srcB : idx0;
    uint4 vA = h[(size_t)srcA * 64 + pbase];
    uint4 vB = h[(size_t)srcB * 64 + pbase];
    PMX4(vA);
    PMX4(vB);
  }
  if (g < ngrp) {
    int s0 = g * 8 + sub;
    int src = __shfl((g < 8) ? e1 : e2, s0 & 63);
    src = (s0 < deg) ? src : idx0;
    uint4 v = h[(size_t)src * 64 + pbase];
    PMX4(v);
  }

  // reduce across the 8 source-slots (lane groups of 8): xor 8, 16, 32
#pragma unroll
  for (int d = 8; d <= 32; d <<= 1) {
    pmax(a0, (unsigned)__shfl_xor((int)a0, d));
    pmax(a1, (unsigned)__shfl_xor((int)a1, d));
    pmax(a2, (unsigned)__shfl_xor((int)a2, d));
    pmax(a3, (unsigned)__shfl_xor((int)a3, d));
  }

  if (lane < 8) {
    float4 o0, o1;
    if (deg == 0) {
      o0 = make_float4(0.f, 0.f, 0.f, 0.f);
      o1 = o0;
    } else {
      o0 = make_float4(dec16(a0 & 0xFFFFu), dec16(a0 >> 16),
                       dec16(a1 & 0xFFFFu), dec16(a1 >> 16));
      o1 = make_float4(dec16(a2 & 0xFFFFu), dec16(a2 >> 16),
                       dec16(a3 & 0xFFFFu), dec16(a3 >> 16));
    }
    out[(size_t)n * 128 + p * 16 + lane * 2] = o0;
    out[(size_t)n * 128 + p * 16 + lane * 2 + 1] = o1;
  }
}

// ---------- launcher ----------
extern "C" void kernel_launch(void* const* d_in, const int* in_sizes, int n_in,
                              void* d_out, int out_size, void* d_ws, size_t ws_size,
                              hipStream_t stream) {
  const float* x = (const float*)d_in[0];
  const int* ei = (const int*)d_in[1];
  const float* W = (const float*)d_in[2];
  const float* b = (const float*)d_in[3];
  float* out = (float*)d_out;

  char* ws = (char*)d_ws;
  uint4* h = (uint4*)ws;                                   // 20,480,000 B
  int* cnt = (int*)(ws + 20480000);                        // 20,000 x 4 = 80,000 B
  unsigned short* csr = (unsigned short*)(ws + 20560000);  // 20000*128*2 = 5,120,000 B
  unsigned short* Wbf = (unsigned short*)(ws + 25680000);  // 32,768 B

  init_kernel<<<(N_NODES + 255) / 256, 256, 0, stream>>>(W, Wbf, cnt);
  scatter_kernel<<<N_EDGES / 256, 256, 0, stream>>>(ei, cnt, csr);
  gemm_kernel<<<N_NODES / 16, 256, 0, stream>>>((const float4*)x, Wbf, b, h);
  agg_kernel<<<(N_NODES / 4) * NPHASE, 256, 0, stream>>>(h, cnt, csr, (float4*)out);
}

// Round 3
// 201.059 us; speedup vs baseline: 1.0144x; 1.0144x over previous
//
#include <hip/hip_runtime.h>
#include <hip/hip_bf16.h>
#include <stdint.h>

#define N_NODES 20000
#define N_EDGES 640000
#define FEAT 128
#define CAPD 128   // per-dst list cap; deg ~ Poisson(32), P(>128) ~ 1e-43
#define NPHASE 8   // o-feature slices of 16 (2.56 MB h-slice, L2-resident per XCD)

typedef __attribute__((ext_vector_type(8))) short bf16x8;
typedef __attribute__((ext_vector_type(4))) float f32x4;

// ---------- helpers ----------
// packed f32x2 -> bf16x2 (v_cvt_pk_bf16_f32), lo in low half
__device__ __forceinline__ unsigned pkbf16(float lo, float hi) {
  __hip_bfloat162 p = __float22bfloat162_rn(make_float2(lo, hi));
  return *reinterpret_cast<unsigned*>(&p);
}

// order-preserving encode: f32 -> RNE-rounded bf16 -> monotone u16
__device__ __forceinline__ unsigned short enc16(float f) {
  unsigned a = __float_as_uint(f);
  unsigned b = (a + 0x7FFFu + ((a >> 16) & 1u)) >> 16;  // RNE to bf16
  unsigned s = (unsigned)((int)a >> 31);                // 0 or ~0
  return (unsigned short)((b ^ 0x8000u) ^ (s & 0x7FFFu));
}

// inverse of enc16 (result as f32)
__device__ __forceinline__ float dec16(unsigned e) {
  unsigned b = (e & 0x8000u) ? (e ^ 0x8000u) : (e ^ 0xFFFFu);
  return __uint_as_float(b << 16);
}

// packed 2x u16 max
__device__ __forceinline__ void pmax(unsigned& a, unsigned v) {
  asm("v_pk_max_u16 %0, %0, %1" : "+v"(a) : "v"(v));
}

#define PMX4(v)                                              \
  do {                                                       \
    pmax(a0, (v).x); pmax(a1, (v).y);                        \
    pmax(a2, (v).z); pmax(a3, (v).w);                        \
  } while (0)

// ---------- kernel 1: zero cnt + convert W -> bf16 ([o][f] layout) ----------
__global__ void init_kernel(const float* __restrict__ W,
                            unsigned short* __restrict__ Wbf,
                            int* __restrict__ cnt) {
  int i = blockIdx.x * 256 + threadIdx.x;
  if (i < N_NODES) cnt[i] = 0;
  if (i < FEAT * FEAT / 2) {
    float2 w = ((const float2*)W)[i];
    ((unsigned*)Wbf)[i] = pkbf16(w.x, w.y);
  }
}

// ---------- kernel 2: edge scatter into TRANSPOSED per-dst lists ----------
// entry j stored at position (j&64) | 8*(j&7) | ((j>>3)&7): agg lane `sub`
// then preloads its 8 needed entries {sub, 8+sub, ...} as ONE uint4.
__global__ __launch_bounds__(256) void scatter_kernel(const int* __restrict__ ei,
                                                      int* __restrict__ cnt,
                                                      unsigned short* __restrict__ csrT) {
  int e = blockIdx.x * 256 + threadIdx.x;
  int src = ei[e];
  int dst = ei[N_EDGES + e];
  int pos = atomicAdd(&cnt[dst], 1);
  if (pos < CAPD) {
    int tp = (pos & 64) | ((pos & 7) << 3) | ((pos >> 3) & 7);
    csrT[(size_t)dst * CAPD + tp] = (unsigned short)src;
  }
}

// ---------- kernel 3: MFMA GEMM + bias -> h (order-preserving u16-encoded) ----------
__global__ __launch_bounds__(256) void gemm_kernel(
    const float4* __restrict__ x, const unsigned short* __restrict__ Wbf,
    const float* __restrict__ b, uint4* __restrict__ h) {
  // x-stage: [t][16 n][136 f] bf16 = 17408 B.  h-stage (aliased): [16 n][520] u16.
  __shared__ __align__(16) unsigned short sm[17408 / 2];
  const int tid = threadIdx.x;
  const int n0 = blockIdx.x * 16;

#pragma unroll
  for (int it = 0; it < 4; ++it) {
    int e = tid + it * 256;       // 16 n x 64 f-pairs
    int n = e >> 6, fp = e & 63;  // f = 2*fp
    float4 a = x[(size_t)(n0 + n) * 128 + 2 * fp];
    float4 c = x[(size_t)(n0 + n) * 128 + 2 * fp + 1];
    ((unsigned*)sm)[(0 * 16 + n) * 68 + fp] = pkbf16(a.x, c.x);
    ((unsigned*)sm)[(1 * 16 + n) * 68 + fp] = pkbf16(a.y, c.y);
    ((unsigned*)sm)[(2 * 16 + n) * 68 + fp] = pkbf16(a.z, c.z);
    ((unsigned*)sm)[(3 * 16 + n) * 68 + fp] = pkbf16(a.w, c.w);
  }

  __syncthreads();

  const int wv = tid >> 6;  // t
  const int l = tid & 63;
  const int col = l & 15;
  const int quad = l >> 4;

  f32x4 acc[8];
#pragma unroll
  for (int os = 0; os < 8; ++os) {
    float bv = b[os * 16 + col];
    acc[os] = (f32x4){bv, bv, bv, bv};
  }

#pragma unroll
  for (int k = 0; k < 4; ++k) {
    bf16x8 af = *(const bf16x8*)&sm[(wv * 16 + col) * 136 + k * 32 + quad * 8];
#pragma unroll
    for (int os = 0; os < 8; ++os) {
      bf16x8 bfv = *(const bf16x8*)&Wbf[(os * 16 + col) * 128 + k * 32 + quad * 8];
      acc[os] = __builtin_amdgcn_mfma_f32_16x16x32_bf16(af, bfv, acc[os], 0, 0, 0);
    }
  }

  __syncthreads();

  // C layout: D[m = quad*4 + r][o = os*16 + col]; h-stage LDS [n][o][t], row 520 u16.
#pragma unroll
  for (int os = 0; os < 8; ++os) {
#pragma unroll
    for (int r = 0; r < 4; ++r) {
      sm[(quad * 4 + r) * 520 + (os * 16 + col) * 4 + wv] = enc16(acc[os][r]);
    }
  }
  __syncthreads();

#pragma unroll
  for (int it = 0; it < 4; ++it) {
    int e = tid + it * 256;
    int n = e >> 6, q = e & 63;
    uint4 v = *(const uint4*)&sm[n * 520 + q * 8];
    h[(size_t)(n0 + n) * 64 + q] = v;
  }
}

// ---------- kernel 4: o-phased max aggregation, shuffle-free gather ----------
// phase = blockIdx.x & 7 == XCD: each XCD keeps its 2.56 MB h-slice in L2.
// One wave per dst per phase. Each lane preloads its index column (uint4),
// inner loop = extract + clamp + 32-bit addr + dwordx4 load + 4x v_pk_max_u16.
// Loads hand-batched 4-wide / 2-wide for MLP; all guards wave-uniform.
__global__ __launch_bounds__(256) void agg_kernel(
    const uint4* __restrict__ h, const int* __restrict__ cnt,
    const unsigned short* __restrict__ csrT, float4* __restrict__ out) {
  const int bid = blockIdx.x;
  const int p = bid & 7;
  const int grp = bid >> 3;
  const int w = threadIdx.x >> 6;
  const int lane = threadIdx.x & 63;
  const int n = grp * 4 + w;
  const int sub = lane >> 3;  // source slot within a group of 8
  const int oq = lane & 7;    // o-pair slot (2 o x 4 t = 16 B)

  int deg = cnt[n];
  deg = deg > CAPD ? CAPD : deg;

  // per-lane index column: entries {sub + 8i}, i=0..7 (block 0 of 64)
  const char* cb = (const char*)csrT + (size_t)n * 256 + sub * 16;
  uint4 ia = *(const uint4*)cb;

  unsigned a0 = 0x007F007Fu, a1 = a0, a2 = a0, a3 = a0;  // enc(-inf) packed

  const char* hb = (const char*)h;
  const unsigned pb = (((unsigned)p * 8 + oq) << 4);  // byte offset within h row

#define GETLO(wrd) ((int)((wrd) & 0xFFFFu))
#define GETHI(wrd) ((int)((wrd) >> 16))
#define LDS4(iv, idv, I)                                          \
  {                                                               \
    int id_ = ((I)*8 + sub < deg) ? (idv) : idx0;                 \
    iv = *(const uint4*)(hb + (((unsigned)id_ << 10) + pb));      \
  }

  if (deg > 0) {
    // entry 0 sits in slot 0 (low half of ia.x) of lanes 0..7
    int idx0 = __shfl(GETLO(ia.x), 0);
    uint4 v0, v1, v2, v3;
    // slots 0-3 (entries 0..31) unconditional
    LDS4(v0, GETLO(ia.x), 0);
    LDS4(v1, GETHI(ia.x), 1);
    LDS4(v2, GETLO(ia.y), 2);
    LDS4(v3, GETHI(ia.y), 3);
    PMX4(v0); PMX4(v1); PMX4(v2); PMX4(v3);
    if (deg > 32) {
      LDS4(v0, GETLO(ia.z), 4);
      LDS4(v1, GETHI(ia.z), 5);
      PMX4(v0); PMX4(v1);
      if (deg > 48) {
        LDS4(v2, GETLO(ia.w), 6);
        LDS4(v3, GETHI(ia.w), 7);
        PMX4(v2); PMX4(v3);
      }
    }
    if (deg > 64) {  // rare (P ~ 3e-7 per dst)
      uint4 ib = *(const uint4*)(cb + 128);
      LDS4(v0, GETLO(ib.x), 8);
      LDS4(v1, GETHI(ib.x), 9);
      LDS4(v2, GETLO(ib.y), 10);
      LDS4(v3, GETHI(ib.y), 11);
      PMX4(v0); PMX4(v1); PMX4(v2); PMX4(v3);
      if (deg > 96) {
        LDS4(v0, GETLO(ib.z), 12);
        LDS4(v1, GETHI(ib.z), 13);
        LDS4(v2, GETLO(ib.w), 14);
        LDS4(v3, GETHI(ib.w), 15);
        PMX4(v0); PMX4(v1); PMX4(v2); PMX4(v3);
      }
    }
  }

  // reduce across the 8 source-slots (lane groups of 8): xor 8, 16, 32
#pragma unroll
  for (int d = 8; d <= 32; d <<= 1) {
    pmax(a0, (unsigned)__shfl_xor((int)a0, d));
    pmax(a1, (unsigned)__shfl_xor((int)a1, d));
    pmax(a2, (unsigned)__shfl_xor((int)a2, d));
    pmax(a3, (unsigned)__shfl_xor((int)a3, d));
  }

  if (lane < 8) {
    float4 o0, o1;
    if (deg == 0) {
      o0 = make_float4(0.f, 0.f, 0.f, 0.f);
      o1 = o0;
    } else {
      o0 = make_float4(dec16(a0 & 0xFFFFu), dec16(a0 >> 16),
                       dec16(a1 & 0xFFFFu), dec16(a1 >> 16));
      o1 = make_float4(dec16(a2 & 0xFFFFu), dec16(a2 >> 16),
                       dec16(a3 & 0xFFFFu), dec16(a3 >> 16));
    }
    out[(size_t)n * 128 + p * 16 + lane * 2] = o0;
    out[(size_t)n * 128 + p * 16 + lane * 2 + 1] = o1;
  }
}

// ---------- launcher ----------
extern "C" void kernel_launch(void* const* d_in, const int* in_sizes, int n_in,
                              void* d_out, int out_size, void* d_ws, size_t ws_size,
                              hipStream_t stream) {
  const float* x = (const float*)d_in[0];
  const int* ei = (const int*)d_in[1];
  const float* W = (const float*)d_in[2];
  const float* b = (const float*)d_in[3];
  float* out = (float*)d_out;

  char* ws = (char*)d_ws;
  uint4* h = (uint4*)ws;                                    // 20,480,000 B
  int* cnt = (int*)(ws + 20480000);                         // 20,000 x 4 = 80,000 B
  unsigned short* csrT = (unsigned short*)(ws + 20560000);  // 20000*128*2 = 5,120,000 B
  unsigned short* Wbf = (unsigned short*)(ws + 25680000);   // 32,768 B

  init_kernel<<<(N_NODES + 255) / 256, 256, 0, stream>>>(W, Wbf, cnt);
  scatter_kernel<<<N_EDGES / 256, 256, 0, stream>>>(ei, cnt, csrT);
  gemm_kernel<<<N_NODES / 16, 256, 0, stream>>>((const float4*)x, Wbf, b, h);
  agg_kernel<<<(N_NODES / 4) * NPHASE, 256, 0, stream>>>(h, cnt, csrT, (float4*)out);
}